// Round 8
// baseline (3165.194 us; speedup 1.0000x reference)
//
#include <hip/hip_runtime.h>

typedef __bf16 bf16x8 __attribute__((ext_vector_type(8)));
typedef float f32x4 __attribute__((ext_vector_type(4)));
typedef unsigned int u32x4 __attribute__((ext_vector_type(4)));

#define S_LEN 256
#define BATCH 64
#define HID   1024
#define NWG   256
#define SBH   (S_LEN * BATCH * HID)   /* 16777216 */
#define BH    (BATCH * HID)           /* 65536 */
#define CHUNK 32                      /* timesteps of xz materialized at once */
#define NCHUNK (S_LEN / CHUNK)

__device__ __forceinline__ float sigm(float v) { return 1.0f / (1.0f + __expf(-v)); }
__device__ __forceinline__ float tanh_fast(float v) {
  float e = __expf(-2.0f * __builtin_fabsf(v));
  float r = (1.0f - e) / (1.0f + e);
  return __builtin_copysignf(r, v);
}

// Pack 8 f32 -> 8 bf16 (RNE) into one 16B word.
__device__ __forceinline__ u32x4 cvt8(float4 a, float4 b) {
  union { unsigned short us[8]; u32x4 v; } r;
  r.us[0] = __builtin_bit_cast(unsigned short, (__bf16)a.x);
  r.us[1] = __builtin_bit_cast(unsigned short, (__bf16)a.y);
  r.us[2] = __builtin_bit_cast(unsigned short, (__bf16)a.z);
  r.us[3] = __builtin_bit_cast(unsigned short, (__bf16)a.w);
  r.us[4] = __builtin_bit_cast(unsigned short, (__bf16)b.x);
  r.us[5] = __builtin_bit_cast(unsigned short, (__bf16)b.y);
  r.us[6] = __builtin_bit_cast(unsigned short, (__bf16)b.z);
  r.us[7] = __builtin_bit_cast(unsigned short, (__bf16)b.w);
  return r.v;
}

// 8 x global_load_dwordx4 + internal vmcnt(0) in ONE asm block (proven safe:
// no in-flight registers ever visible to the register allocator).
#define LOAD8_X4(dst, base, MODS)                                             \
  asm volatile(                                                               \
      "global_load_dwordx4 %0, %8, off offset:0 " MODS "\n\t"                 \
      "global_load_dwordx4 %1, %8, off offset:64 " MODS "\n\t"                \
      "global_load_dwordx4 %2, %8, off offset:128 " MODS "\n\t"               \
      "global_load_dwordx4 %3, %8, off offset:192 " MODS "\n\t"               \
      "global_load_dwordx4 %4, %8, off offset:256 " MODS "\n\t"               \
      "global_load_dwordx4 %5, %8, off offset:320 " MODS "\n\t"               \
      "global_load_dwordx4 %6, %8, off offset:384 " MODS "\n\t"               \
      "global_load_dwordx4 %7, %8, off offset:448 " MODS "\n\t"               \
      "s_waitcnt vmcnt(0)"                                                    \
      : "=&v"((dst)[0]), "=&v"((dst)[1]), "=&v"((dst)[2]), "=&v"((dst)[3]),   \
        "=&v"((dst)[4]), "=&v"((dst)[5]), "=&v"((dst)[6]), "=&v"((dst)[7])    \
      : "v"(base)                                                             \
      : "memory")

#define CHECK8(H, MEXP, BAD)                                                  \
  do {                                                                        \
    BAD = 0;                                                                  \
    _Pragma("unroll")                                                         \
    for (int _kc = 0; _kc < 8; ++_kc) {                                       \
      u32x4 _w = (H)[_kc];                                                    \
      BAD |= ((_w[0] ^ (MEXP)) & 0x00010001u);                                \
      BAD |= ((_w[1] ^ (MEXP)) & 0x00010001u);                                \
      BAD |= ((_w[2] ^ (MEXP)) & 0x00010001u);                                \
      BAD |= ((_w[3] ^ (MEXP)) & 0x00010001u);                                \
    }                                                                         \
  } while (0)

// 8 independent gate-col chains x 8 K-fragments (64 MFMA).
#define MFMA8_ALL(A)                                                          \
  do {                                                                        \
    _Pragma("unroll")                                                         \
    for (int _kc = 0; _kc < 8; ++_kc) {                                       \
      bf16x8 _a = __builtin_bit_cast(bf16x8, (A)[_kc]);                       \
      acc0 = __builtin_amdgcn_mfma_f32_16x16x32_bf16(_a, __builtin_bit_cast(bf16x8, Braw[ 0 + _kc]), acc0, 0, 0, 0); \
      acc1 = __builtin_amdgcn_mfma_f32_16x16x32_bf16(_a, __builtin_bit_cast(bf16x8, Braw[ 8 + _kc]), acc1, 0, 0, 0); \
      acc2 = __builtin_amdgcn_mfma_f32_16x16x32_bf16(_a, __builtin_bit_cast(bf16x8, Braw[16 + _kc]), acc2, 0, 0, 0); \
      acc3 = __builtin_amdgcn_mfma_f32_16x16x32_bf16(_a, __builtin_bit_cast(bf16x8, Braw[24 + _kc]), acc3, 0, 0, 0); \
      acc4 = __builtin_amdgcn_mfma_f32_16x16x32_bf16(_a, __builtin_bit_cast(bf16x8, Braw[32 + _kc]), acc4, 0, 0, 0); \
      acc5 = __builtin_amdgcn_mfma_f32_16x16x32_bf16(_a, __builtin_bit_cast(bf16x8, Braw[40 + _kc]), acc5, 0, 0, 0); \
      acc6 = __builtin_amdgcn_mfma_f32_16x16x32_bf16(_a, __builtin_bit_cast(bf16x8, Braw[48 + _kc]), acc6, 0, 0, 0); \
      acc7 = __builtin_amdgcn_mfma_f32_16x16x32_bf16(_a, __builtin_bit_cast(bf16x8, Braw[56 + _kc]), acc7, 0, 0, 0); \
    }                                                                         \
  } while (0)

// Resident-W loader: gate G, sub-tile sub, on-the-fly f32->bf16. KOFF=0 -> Wx
// half, KOFF=1024 -> Wh half. ct = G*2+sub; local col ct*16+l16.
#define LOADW_G(W, G, KOFF)                                                   \
  {                                                                           \
    _Pragma("unroll")                                                         \
    for (int sub = 0; sub < 2; ++sub) {                                       \
      const float* rp = (W) + (size_t)(u * 32 + sub * 16 + l16) * 2048 +      \
                        (KOFF) + kbase + kq8;                                 \
      _Pragma("unroll")                                                       \
      for (int kc = 0; kc < 8; ++kc) {                                        \
        float4 lo = *(const float4*)(rp + kc * 32);                           \
        float4 hi = *(const float4*)(rp + kc * 32 + 4);                       \
        Braw[((G) * 2 + sub) * 8 + kc] = cvt8(lo, hi);                        \
      }                                                                       \
    }                                                                         \
  }
#define LOADW(KOFF)                                                           \
  do {                                                                        \
    LOADW_G(Wf, 0, KOFF) LOADW_G(Wi, 1, KOFF)                                 \
    LOADW_G(Wg, 2, KOFF) LOADW_G(Wo, 3, KOFF)                                 \
  } while (0)

// Prep: h_buf region0 = h0 bf16 with epoch bit0=0; region1 poison bit0=1;
// xcc slots = -1.
__global__ void prep_kernel(const float* __restrict__ h0,
                            __bf16* __restrict__ h_buf, int* __restrict__ xccs) {
  size_t tid = (size_t)blockIdx.x * blockDim.x + threadIdx.x;
  size_t stride = (size_t)gridDim.x * blockDim.x;
  for (size_t i = tid; i < (size_t)(BH / 8); i += stride) {
    const float4* s = (const float4*)h0 + i * 2;
    u32x4 v = cvt8(s[0], s[1]);
    v &= 0xFFFEFFFEu;
    ((u32x4*)h_buf)[i] = v;
  }
  for (size_t i = tid; i < (size_t)(BH / 8); i += stride) {
    u32x4 p = {0x00010001u, 0x00010001u, 0x00010001u, 0x00010001u};
    ((u32x4*)(h_buf + BH))[i] = p;
  }
  for (size_t i = tid; i < NWG; i += stride) xccs[i] = -1;
}

// v8: XCD-local groups. 8 groups (= batch-tiles of 8) x 32 WGs (32 units each).
// group = wgid&7 -> with round-robin dispatch all 32 WGs of a group share one
// XCD; verified at runtime via HW_REG_XCC_ID handshake. Verified -> h exchange
// uses sc0-only (XCD-L2 coherent, ~5x lower RT); else sc0 sc1 (LLC, proven).
// Register wall broken by in-kernel xz precompute: per 32-step chunk, phase-1
// holds Wx resident and computes xz = x.Wx^T (2 timesteps packed per MFMA in
// the free M-rows), stored f32 to ws (self-produced/self-consumed per WG -> no
// sync, plain cached access). Phase-2 holds Wh resident; per step: epoch-marker
// poll of h (v4 protocol), 64 MFMA, LDS combine (+xz+bias), publish.
__global__ __launch_bounds__(256, 1) void lstm_kernel(
    const float* __restrict__ x, const float* __restrict__ c0,
    const float* __restrict__ bfp, const float* __restrict__ bip,
    const float* __restrict__ bgp, const float* __restrict__ bop,
    const float* __restrict__ Wf, const float* __restrict__ Wi,
    const float* __restrict__ Wg, const float* __restrict__ Wo,
    __bf16* __restrict__ h_buf, float* __restrict__ xz,
    int* __restrict__ xccs, float* __restrict__ out) {
  const int tid  = threadIdx.x;
  const int wgid = blockIdx.x;
  const int g    = wgid & 7;            // batch group (target: one XCD)
  const int u    = wgid >> 3;           // unit tile: units [32u, 32u+32)
  const int wave = tid >> 6;
  const int lane = tid & 63;
  const int l16  = lane & 15;
  const int kq8  = (lane >> 4) * 8;
  const int kbase = wave * 256;         // per-wave K-quarter
  const int cb = tid >> 5;              // combine: batch-local 0..7
  const int cu = tid & 31;              // combine: unit-local 0..31
  const int j  = u * 32 + cu;           // global hidden unit
  const int bg = g * 8 + cb;            // global batch

  __shared__ float zb[2][4][16][128];   // parity x wave x row x localcol (64KB)
  __shared__ unsigned short hpack[8][32];
  __shared__ int fast_sh;

  // ---- XCC handshake: verify all 32 group members share an XCD ----
  {
    int xcc;
    asm volatile("s_getreg_b32 %0, hwreg(HW_REG_XCC_ID)" : "=s"(xcc));
    if (tid == 0)
      __hip_atomic_store(&xccs[wgid], xcc, __ATOMIC_RELAXED, __HIP_MEMORY_SCOPE_AGENT);
    if (tid < 64) {
      int slot = g + (lane & 31) * 8;   // the 32 wgids of this group (dup x2)
      int v;
      for (;;) {
        v = __hip_atomic_load(&xccs[slot], __ATOMIC_RELAXED, __HIP_MEMORY_SCOPE_AGENT);
        if (__ballot(v < 0) == 0ull) break;
        __builtin_amdgcn_s_sleep(1);
      }
      int v0 = __shfl(v, 0);
      if (tid == 0) fast_sh = (__ballot(v == v0) == ~0ull) ? 1 : 0;
    }
    __syncthreads();
  }
  const bool fast = (fast_sh != 0);

  // ---- Per-thread recurrent state ----
  float c = c0[(size_t)bg * HID + j];
  const float bias_f = bfp[j], bias_i = bip[j], bias_g = bgp[j], bias_o = bop[j];

  u32x4 Braw[64];                       // resident weights (Wx or Wh per phase)

  for (int ch = 0; ch < NCHUNK; ++ch) {
    // ================= PHASE 1: xz for t in [ch*32, ch*32+32) =================
    LOADW(0);                           // Wx resident
    for (int it = 0; it < CHUNK / 2; ++it) {
      const int t2 = ch * CHUNK + it * 2;
      const int par = it & 1;
      // A: rows 0-7 = x(t2), rows 8-15 = x(t2+1); batch = lane&7
      u32x4 Ax[8];
      {
        const float* xp = x + ((size_t)(t2 + ((lane & 15) >> 3)) * BATCH +
                               g * 8 + (lane & 7)) * HID + kbase + kq8;
#pragma unroll
        for (int kc = 0; kc < 8; ++kc) {
          float4 lo = *(const float4*)(xp + kc * 32);
          float4 hi = *(const float4*)(xp + kc * 32 + 4);
          Ax[kc] = cvt8(lo, hi);
        }
      }
      f32x4 acc0 = {0,0,0,0}, acc1 = {0,0,0,0}, acc2 = {0,0,0,0}, acc3 = {0,0,0,0};
      f32x4 acc4 = {0,0,0,0}, acc5 = {0,0,0,0}, acc6 = {0,0,0,0}, acc7 = {0,0,0,0};
      MFMA8_ALL(Ax);
#pragma unroll
      for (int r = 0; r < 4; ++r) {
        int row = (lane >> 4) * 4 + r;
        zb[par][wave][row][  0 + l16] = acc0[r];
        zb[par][wave][row][ 16 + l16] = acc1[r];
        zb[par][wave][row][ 32 + l16] = acc2[r];
        zb[par][wave][row][ 48 + l16] = acc3[r];
        zb[par][wave][row][ 64 + l16] = acc4[r];
        zb[par][wave][row][ 80 + l16] = acc5[r];
        zb[par][wave][row][ 96 + l16] = acc6[r];
        zb[par][wave][row][112 + l16] = acc7[r];
      }
      __syncthreads();
      // combine 4 wave partials; store xz (chunk-local t, global batch, gcol)
      {
        int s2 = tid >> 7, bb = (tid >> 4) & 7, cg = tid & 15;
        int row = s2 * 8 + bb;
        float v[8];
#pragma unroll
        for (int ci = 0; ci < 8; ++ci) {
          int col = cg * 8 + ci;
          v[ci] = zb[par][0][row][col] + zb[par][1][row][col] +
                  zb[par][2][row][col] + zb[par][3][row][col];
        }
        size_t base = ((size_t)((it * 2 + s2) * BATCH + g * 8 + bb)) * 4096 +
                      (size_t)(cg >> 2) * 1024 + u * 32 + (cg & 3) * 8;
        *(float4*)(xz + base)     = (float4){v[0], v[1], v[2], v[3]};
        *(float4*)(xz + base + 4) = (float4){v[4], v[5], v[6], v[7]};
      }
    }

    // ================= PHASE 2: recurrence steps [ch*32, ch*32+32) ============
    LOADW(1024);                        // Wh resident
    __syncthreads();                    // all phase-1 zb reads done before reuse
    // xz prefetch for first step of the chunk (plain cached loads, self-made)
    float xzp0, xzp1, xzp2, xzp3;
    {
      const float* xp = xz + (size_t)(0 * BATCH + bg) * 4096 + j;
      xzp0 = xp[0]; xzp1 = xp[1024]; xzp2 = xp[2048]; xzp3 = xp[3072];
    }

    for (int tl = 0; tl < CHUNK; ++tl) {
      const int t = ch * CHUNK + tl;
      const size_t roff = (t & 1) ? (size_t)BH : 0;
      const size_t woff = (t & 1) ? 0 : (size_t)BH;
      const unsigned mexp = ((unsigned)(t >> 1) & 1u) * 0x00010001u;
      const int par = tl & 1;

      // ---- poll h (epoch-marker protocol; mode selects cache scope) ----
      u32x4 Ah[8];
      {
        unsigned long ga = (unsigned long)(h_buf + roff +
                           (size_t)(g * 8 + (lane & 7)) * HID + kbase + kq8);
        unsigned bad;
        if (fast) {
          LOAD8_X4(Ah, ga, "sc0");
          CHECK8(Ah, mexp, bad);
          while (__builtin_expect(__ballot(bad != 0) != 0ull, 0)) {
            __builtin_amdgcn_s_sleep(1);
            LOAD8_X4(Ah, ga, "sc0");
            CHECK8(Ah, mexp, bad);
          }
        } else {
          LOAD8_X4(Ah, ga, "sc0 sc1");
          CHECK8(Ah, mexp, bad);
          while (__builtin_expect(__ballot(bad != 0) != 0ull, 0)) {
            __builtin_amdgcn_s_sleep(1);
            LOAD8_X4(Ah, ga, "sc0 sc1");
            CHECK8(Ah, mexp, bad);
          }
        }
      }

      f32x4 acc0 = {0,0,0,0}, acc1 = {0,0,0,0}, acc2 = {0,0,0,0}, acc3 = {0,0,0,0};
      f32x4 acc4 = {0,0,0,0}, acc5 = {0,0,0,0}, acc6 = {0,0,0,0}, acc7 = {0,0,0,0};
      MFMA8_ALL(Ah);

      if (lane < 32) {                  // rows 0-7 real; 8-15 are batch dups
#pragma unroll
        for (int r = 0; r < 4; ++r) {
          int row = (lane >> 4) * 4 + r;
          zb[par][wave][row][  0 + l16] = acc0[r];
          zb[par][wave][row][ 16 + l16] = acc1[r];
          zb[par][wave][row][ 32 + l16] = acc2[r];
          zb[par][wave][row][ 48 + l16] = acc3[r];
          zb[par][wave][row][ 64 + l16] = acc4[r];
          zb[par][wave][row][ 80 + l16] = acc5[r];
          zb[par][wave][row][ 96 + l16] = acc6[r];
          zb[par][wave][row][112 + l16] = acc7[r];
        }
      }
      __syncthreads();

      // ---- combine: z = xz + Wh.h partials + bias; update c, h ----
      float h;
      {
        float zf = zb[par][0][cb][ 0 + cu] + zb[par][1][cb][ 0 + cu] +
                   zb[par][2][cb][ 0 + cu] + zb[par][3][cb][ 0 + cu] + xzp0 + bias_f;
        float zi = zb[par][0][cb][32 + cu] + zb[par][1][cb][32 + cu] +
                   zb[par][2][cb][32 + cu] + zb[par][3][cb][32 + cu] + xzp1 + bias_i;
        float zg = zb[par][0][cb][64 + cu] + zb[par][1][cb][64 + cu] +
                   zb[par][2][cb][64 + cu] + zb[par][3][cb][64 + cu] + xzp2 + bias_g;
        float zo = zb[par][0][cb][96 + cu] + zb[par][1][cb][96 + cu] +
                   zb[par][2][cb][96 + cu] + zb[par][3][cb][96 + cu] + xzp3 + bias_o;
        float fg = sigm(zf);
        float ig = sigm(zi);
        float gg = tanh_fast(zg);
        float og = sigm(zo);
        c = fg * c + ig * gg;
        h = og * tanh_fast(c);
      }

      if (t < S_LEN - 1) {
        // ---- publish h with next epoch marker (within-wave pack) ----
        {
          unsigned short hb = __builtin_bit_cast(unsigned short, (__bf16)h);
          hb = (unsigned short)((hb & 0xFFFEu) | (unsigned)(((t + 1) >> 1) & 1));
          hpack[cb][cu] = hb;
        }
        asm volatile("s_waitcnt lgkmcnt(0)" ::: "memory");
        __builtin_amdgcn_sched_barrier(0);
        if (lane < 8) {                 // wave w publishes its own rows 2w,2w+1
          int row = 2 * wave + (lane >> 2), seg = lane & 3;
          u32x4 hv = *(const u32x4*)(&hpack[row][seg * 8]);
          unsigned long ha = (unsigned long)(h_buf + woff +
                             (size_t)(g * 8 + row) * HID + u * 32 + seg * 8);
          if (fast) {
            asm volatile("global_store_dwordx4 %0, %1, off sc0"
                         :: "v"(ha), "v"(hv) : "memory");
          } else {
            asm volatile("global_store_dwordx4 %0, %1, off sc0 sc1"
                         :: "v"(ha), "v"(hv) : "memory");
          }
        }
        // ---- window: out-write + xz prefetch for next step ----
        {
          size_t oi = ((size_t)(t * BATCH + bg)) * HID + j;
          out[oi] = x[oi] + h;
        }
        if (tl < CHUNK - 1) {
          const float* xp = xz + (size_t)((tl + 1) * BATCH + bg) * 4096 + j;
          xzp0 = xp[0]; xzp1 = xp[1024]; xzp2 = xp[2048]; xzp3 = xp[3072];
        }
      } else {
        size_t oi = ((size_t)(t * BATCH + bg)) * HID + j;
        out[oi] = x[oi] + h;
        out[(size_t)SBH + (size_t)bg * HID + j] = h;          // h_f
        out[(size_t)SBH + BH + (size_t)bg * HID + j] = c;     // c_f
      }
    }
    __syncthreads();                    // drain before next chunk reuses zb
  }
}

extern "C" void kernel_launch(void* const* d_in, const int* in_sizes, int n_in,
                              void* d_out, int out_size, void* d_ws, size_t ws_size,
                              hipStream_t stream) {
  const float* x   = (const float*)d_in[0];
  const float* h0  = (const float*)d_in[1];
  const float* c0  = (const float*)d_in[2];
  const float* Wf  = (const float*)d_in[3];
  const float* bf_ = (const float*)d_in[4];
  const float* Wi  = (const float*)d_in[5];
  const float* bi_ = (const float*)d_in[6];
  const float* Wg  = (const float*)d_in[7];
  const float* bg_ = (const float*)d_in[8];
  const float* Wo  = (const float*)d_in[9];
  const float* bo_ = (const float*)d_in[10];

  char* ws = (char*)d_ws;
  size_t off = 0;
  float* xz = (float*)(ws + off); off += (size_t)CHUNK * BATCH * 4096 * 4;  // 32 MB
  __bf16* h_buf = (__bf16*)(ws + off); off += (size_t)2 * BH * 2;           // 256 KB
  int* xccs = (int*)(ws + off); off += NWG * sizeof(int);
  if (ws_size < off) return;

  float* out = (float*)d_out;

  prep_kernel<<<256, 256, 0, stream>>>(h0, h_buf, xccs);
  lstm_kernel<<<NWG, 256, 0, stream>>>(x, c0, bf_, bi_, bg_, bo_,
                                       Wf, Wi, Wg, Wo, h_buf, xz, xccs, out);
}

// Round 9
// 1874.781 us; speedup vs baseline: 1.6883x; 1.6883x over previous
//
#include <hip/hip_runtime.h>

typedef __bf16 bf16x8 __attribute__((ext_vector_type(8)));
typedef float f32x4 __attribute__((ext_vector_type(4)));
typedef unsigned int u32x4 __attribute__((ext_vector_type(4)));

#define S_LEN 256
#define BATCH 64
#define HID   1024
#define NWG   256
#define SBH   (S_LEN * BATCH * HID)   /* 16777216 */
#define BH    (BATCH * HID)           /* 65536 */

__device__ __forceinline__ float sigm(float v) { return 1.0f / (1.0f + __expf(-v)); }
__device__ __forceinline__ float tanh_fast(float v) {
  float e = __expf(-2.0f * __builtin_fabsf(v));
  float r = (1.0f - e) / (1.0f + e);
  return __builtin_copysignf(r, v);
}

// Pack 8 f32 -> 8 bf16 (RNE via compiler cvt) into one 16B word.
__device__ __forceinline__ u32x4 cvt8(float4 a, float4 b) {
  union { unsigned short us[8]; u32x4 v; } r;
  r.us[0] = __builtin_bit_cast(unsigned short, (__bf16)a.x);
  r.us[1] = __builtin_bit_cast(unsigned short, (__bf16)a.y);
  r.us[2] = __builtin_bit_cast(unsigned short, (__bf16)a.z);
  r.us[3] = __builtin_bit_cast(unsigned short, (__bf16)a.w);
  r.us[4] = __builtin_bit_cast(unsigned short, (__bf16)b.x);
  r.us[5] = __builtin_bit_cast(unsigned short, (__bf16)b.y);
  r.us[6] = __builtin_bit_cast(unsigned short, (__bf16)b.z);
  r.us[7] = __builtin_bit_cast(unsigned short, (__bf16)b.w);
  return r.v;
}

// 8 x global_load_dwordx4 + internal vmcnt(0), ONE asm block.
// PROVEN SAFE pattern: no in-flight registers are ever visible to regalloc
// (rounds 5/6 showed split issue/wait across compiler code is unsound here).
#define LOAD8_X4(dst, base, MODS)                                             \
  asm volatile(                                                               \
      "global_load_dwordx4 %0, %8, off offset:0 " MODS "\n\t"                 \
      "global_load_dwordx4 %1, %8, off offset:64 " MODS "\n\t"                \
      "global_load_dwordx4 %2, %8, off offset:128 " MODS "\n\t"               \
      "global_load_dwordx4 %3, %8, off offset:192 " MODS "\n\t"               \
      "global_load_dwordx4 %4, %8, off offset:256 " MODS "\n\t"               \
      "global_load_dwordx4 %5, %8, off offset:320 " MODS "\n\t"               \
      "global_load_dwordx4 %6, %8, off offset:384 " MODS "\n\t"               \
      "global_load_dwordx4 %7, %8, off offset:448 " MODS "\n\t"               \
      "s_waitcnt vmcnt(0)"                                                    \
      : "=&v"((dst)[0]), "=&v"((dst)[1]), "=&v"((dst)[2]), "=&v"((dst)[3]),   \
        "=&v"((dst)[4]), "=&v"((dst)[5]), "=&v"((dst)[6]), "=&v"((dst)[7])    \
      : "v"(base)                                                             \
      : "memory")

#define CHECK8(H, MEXP, BAD)                                                  \
  do {                                                                        \
    BAD = 0;                                                                  \
    _Pragma("unroll")                                                         \
    for (int _kc = 0; _kc < 8; ++_kc) {                                       \
      u32x4 _w = (H)[_kc];                                                    \
      BAD |= ((_w[0] ^ (MEXP)) & 0x00010001u);                                \
      BAD |= ((_w[1] ^ (MEXP)) & 0x00010001u);                                \
      BAD |= ((_w[2] ^ (MEXP)) & 0x00010001u);                                \
      BAD |= ((_w[3] ^ (MEXP)) & 0x00010001u);                                \
    }                                                                         \
  } while (0)

#define HMFMA(H)                                                              \
  do {                                                                        \
    _Pragma("unroll")                                                         \
    for (int _kc = 0; _kc < 8; ++_kc) {                                       \
      bf16x8 _a = __builtin_bit_cast(bf16x8, (H)[_kc]);                       \
      acc0 = __builtin_amdgcn_mfma_f32_16x16x32_bf16(_a, __builtin_bit_cast(bf16x8, Braw[ 0 + _kc]), acc0, 0, 0, 0); \
      acc1 = __builtin_amdgcn_mfma_f32_16x16x32_bf16(_a, __builtin_bit_cast(bf16x8, Braw[ 8 + _kc]), acc1, 0, 0, 0); \
      acc2 = __builtin_amdgcn_mfma_f32_16x16x32_bf16(_a, __builtin_bit_cast(bf16x8, Braw[16 + _kc]), acc2, 0, 0, 0); \
      acc3 = __builtin_amdgcn_mfma_f32_16x16x32_bf16(_a, __builtin_bit_cast(bf16x8, Braw[24 + _kc]), acc3, 0, 0, 0); \
    }                                                                         \
  } while (0)

// Prep: weights layout-convert to bf16 + h0 seed + region-1 poison.
// (x consumed as f32 directly by lstm_kernel — no 32MB x conversion pass.)
__global__ void prep_kernel(const float* __restrict__ h0,
                            const float* __restrict__ Wf, const float* __restrict__ Wi,
                            const float* __restrict__ Wg, const float* __restrict__ Wo,
                            __bf16* __restrict__ w_x, __bf16* __restrict__ w_h,
                            __bf16* __restrict__ h_buf) {
  size_t tid = (size_t)blockIdx.x * blockDim.x + threadIdx.x;
  size_t stride = (size_t)gridDim.x * blockDim.x;

#define W_CONV(W, gidx)                                                        \
  for (size_t i = tid; i < (size_t)(1024 * 128); i += stride) {                \
    int j   = (int)(i >> 7);                                                   \
    int kc8 = (int)(i & 127);                                                  \
    const float* row = (W) + (size_t)j * 2048;                                 \
    const float4* sx = (const float4*)(row + kc8 * 8);                         \
    const float4* sh = (const float4*)(row + 1024 + kc8 * 8);                  \
    size_t dst = (size_t)((gidx) * 1024 + j) * 128 + kc8;                      \
    ((u32x4*)w_x)[dst] = cvt8(sx[0], sx[1]);                                   \
    ((u32x4*)w_h)[dst] = cvt8(sh[0], sh[1]);                                   \
  }
  W_CONV(Wf, 0)
  W_CONV(Wi, 1)
  W_CONV(Wg, 2)
  W_CONV(Wo, 3)
#undef W_CONV

  // h0 -> bf16, bit0 cleared (epoch marker 0 for consume-step 0)
  for (size_t i = tid; i < (size_t)(BH / 8); i += stride) {
    const float4* s = (const float4*)h0 + i * 2;
    u32x4 v = cvt8(s[0], s[1]);
    v &= 0xFFFEFFFEu;
    ((u32x4*)h_buf)[i] = v;
  }

  // region 1 poison: bit0=1 everywhere (stale vs first producer marker 0)
  for (size_t i = tid; i < (size_t)(BH / 8); i += stride) {
    u32x4 p = {0x00010001u, 0x00010001u, 0x00010001u, 0x00010001u};
    ((u32x4*)(h_buf + BH))[i] = p;
  }
}

// v9 = v4's proven flag-free epoch-marker protocol (957us, best perf+correct)
//   + XOR-swizzled zbuf (PROVEN in r7: SQ_LDS_BANK_CONFLICT 1.68e7 -> 0)
//   + direct f32 x consumption (PROVEN correct in r7/r8; kills 32MB prep pass)
//   - NO early issue of any kind (r5/r6: split asm in-flight regs unsound;
//     r7: atomic-load early issue serializes -> 3ms).
// Poll = single-asm-block load8+vmcnt0 + marker check; stale => full reload.
__global__ __launch_bounds__(256, 1) void lstm_kernel(
    const float* __restrict__ x, const float* __restrict__ c0,
    const float* __restrict__ bfp, const float* __restrict__ bip,
    const float* __restrict__ bgp, const float* __restrict__ bop,
    const __bf16* __restrict__ w_x, const __bf16* __restrict__ w_h,
    __bf16* __restrict__ h_buf, float* __restrict__ out) {
  const int tid    = threadIdx.x;
  const int wgid   = blockIdx.x;
  const int m_idx  = wgid & 3;
  const int m_base = m_idx * 16;
  const int U      = (wgid >> 2) * 16;
  const int wave   = tid >> 6;
  const int lane   = tid & 63;
  const int l16    = lane & 15;
  const int kq8    = (lane >> 4) * 8;
  const int kbase  = wave * 256;

  __shared__ float zbuf[2][4][16][64];       // XOR-swizzled, no pad
  __shared__ unsigned short hpack[16][16];

  // ---- Resident B: 64 frags. [0..31] = Wh (4 gates x 8 kc), [32..63] = Wx ----
  u32x4 Braw[64];
#pragma unroll
  for (int n = 0; n < 4; ++n) {
    unsigned long gbh =
        (unsigned long)(w_h + (size_t)(n * 1024 + U + l16) * HID + kbase + kq8);
    LOAD8_X4(&Braw[n * 8], gbh, "");
  }
#pragma unroll
  for (int n = 0; n < 4; ++n) {
    unsigned long gbx =
        (unsigned long)(w_x + (size_t)(n * 1024 + U + l16) * HID + kbase + kq8);
    LOAD8_X4(&Braw[32 + n * 8], gbx, "");
  }

  const int b_loc  = tid >> 4;
  const int u_loc  = tid & 15;
  const int j_t    = U + u_loc;
  const int b_glob = m_base + b_loc;
  float c = c0[(size_t)b_glob * HID + j_t];
  const float bias_f = bfp[j_t], bias_i = bip[j_t], bias_g = bgp[j_t], bias_o = bop[j_t];

  // ---- Prologue: x(0) partials from f32; x(1) staged ----
  u32x4 Araw_x[8];
  {
    const float* xp = x + (size_t)(m_base + l16) * HID + kbase + kq8;
#pragma unroll
    for (int kc = 0; kc < 8; ++kc) {
      float4 lo = *(const float4*)(xp + kc * 32);
      float4 hi = *(const float4*)(xp + kc * 32 + 4);
      Araw_x[kc] = cvt8(lo, hi);
    }
  }
  f32x4 accx0 = {0,0,0,0}, accx1 = {0,0,0,0}, accx2 = {0,0,0,0}, accx3 = {0,0,0,0};
#pragma unroll
  for (int kc = 0; kc < 8; ++kc) {
    bf16x8 a = __builtin_bit_cast(bf16x8, Araw_x[kc]);
    accx0 = __builtin_amdgcn_mfma_f32_16x16x32_bf16(a, __builtin_bit_cast(bf16x8, Braw[32 +  0 + kc]), accx0, 0, 0, 0);
    accx1 = __builtin_amdgcn_mfma_f32_16x16x32_bf16(a, __builtin_bit_cast(bf16x8, Braw[32 +  8 + kc]), accx1, 0, 0, 0);
    accx2 = __builtin_amdgcn_mfma_f32_16x16x32_bf16(a, __builtin_bit_cast(bf16x8, Braw[32 + 16 + kc]), accx2, 0, 0, 0);
    accx3 = __builtin_amdgcn_mfma_f32_16x16x32_bf16(a, __builtin_bit_cast(bf16x8, Braw[32 + 24 + kc]), accx3, 0, 0, 0);
  }
  {
    const float* xp = x + ((size_t)BATCH + m_base + l16) * HID + kbase + kq8;
#pragma unroll
    for (int kc = 0; kc < 8; ++kc) {
      float4 lo = *(const float4*)(xp + kc * 32);
      float4 hi = *(const float4*)(xp + kc * 32 + 4);
      Araw_x[kc] = cvt8(lo, hi);
    }
  }

  const unsigned long ga_base =
      (unsigned long)(h_buf + (size_t)(m_base + l16) * HID + kbase + kq8);

  for (int t = 0; t < S_LEN; ++t) {
    const size_t roff = (t & 1) ? (size_t)BH : 0;
    const unsigned mexp = ((unsigned)(t >> 1) & 1u) * 0x00010001u;
    const unsigned long ga = ga_base + roff * 2;   // bf16 -> bytes
    const int zp = t & 1;

    // ---- Accept h: load (landed values), check markers; stale => reload ----
    f32x4 acc0 = accx0, acc1 = accx1, acc2 = accx2, acc3 = accx3;
    {
      u32x4 Ah[8];
      LOAD8_X4(Ah, ga, "sc0 sc1");
      unsigned bad;
      CHECK8(Ah, mexp, bad);
      if (__builtin_expect(__ballot(bad != 0) != 0ull, 0)) {
        do {
          __builtin_amdgcn_s_sleep(1);
          LOAD8_X4(Ah, ga, "sc0 sc1");
          CHECK8(Ah, mexp, bad);
        } while (__ballot(bad != 0) != 0ull);
      }
      HMFMA(Ah);
    }

    // ---- z partials to LDS (XOR-swizzled: conflicts == 0, proven r7) ----
    {
      int q = lane >> 4;
#pragma unroll
      for (int r = 0; r < 4; ++r) {
        int row = q * 4 + r;
        int s = ((row ^ (row >> 2)) & 3) << 4;
        zbuf[zp][wave][row][( 0 + l16) ^ s] = acc0[r];
        zbuf[zp][wave][row][(16 + l16) ^ s] = acc1[r];
        zbuf[zp][wave][row][(32 + l16) ^ s] = acc2[r];
        zbuf[zp][wave][row][(48 + l16) ^ s] = acc3[r];
      }
    }
    __syncthreads();   // the only intra-WG barrier per step

    // ---- Combine gates, update c, h ----
    float h;
    {
      const int row = b_loc;
      const int s = ((row ^ (row >> 2)) & 3) << 4;
      float zf = 0.f, zi = 0.f, zg = 0.f, zo = 0.f;
#pragma unroll
      for (int w = 0; w < 4; ++w) {
        zf += zbuf[zp][w][row][( 0 + u_loc) ^ s];
        zi += zbuf[zp][w][row][(16 + u_loc) ^ s];
        zg += zbuf[zp][w][row][(32 + u_loc) ^ s];
        zo += zbuf[zp][w][row][(48 + u_loc) ^ s];
      }
      float fg = sigm(zf + bias_f);
      float ig = sigm(zi + bias_i);
      float gg = tanh_fast(zg + bias_g);
      float og = sigm(zo + bias_o);
      c = fg * c + ig * gg;
      h = og * tanh_fast(c);
    }

    if (t < S_LEN - 1) {
      const size_t woff = (t & 1) ? 0 : (size_t)BH;

      // ---- Publish h with next epoch marker (fire-and-forget) ----
      {
        unsigned short hbv = __builtin_bit_cast(unsigned short, (__bf16)h);
        hbv = (unsigned short)((hbv & 0xFFFEu) | (unsigned)(((t + 1) >> 1) & 1));
        hpack[b_loc][u_loc] = hbv;
      }
      asm volatile("s_waitcnt lgkmcnt(0)" ::: "memory");
      __builtin_amdgcn_sched_barrier(0);
      if (lane < 8) {
        int b = 4 * wave + (lane >> 1), half = lane & 1;
        u32x4 hv = *(const u32x4*)(&hpack[b][half * 8]);
        unsigned long ha = (unsigned long)(h_buf + woff +
                                           (size_t)(m_base + b) * HID + U + half * 8);
        asm volatile("global_store_dwordx4 %0, %1, off sc0 sc1"
                     :: "v"(ha), "v"(hv) : "memory");
      }

      // ---- Window: out-write + x-side MFMA for t+1 + x(t+2) prefetch (f32) ----
      {
        size_t oi = ((size_t)(t * BATCH + b_glob)) * HID + j_t;
        out[oi] = x[oi] + h;
      }
      accx0 = (f32x4){0,0,0,0}; accx1 = (f32x4){0,0,0,0};
      accx2 = (f32x4){0,0,0,0}; accx3 = (f32x4){0,0,0,0};
#pragma unroll
      for (int kc = 0; kc < 8; ++kc) {
        bf16x8 a = __builtin_bit_cast(bf16x8, Araw_x[kc]);
        accx0 = __builtin_amdgcn_mfma_f32_16x16x32_bf16(a, __builtin_bit_cast(bf16x8, Braw[32 +  0 + kc]), accx0, 0, 0, 0);
        accx1 = __builtin_amdgcn_mfma_f32_16x16x32_bf16(a, __builtin_bit_cast(bf16x8, Braw[32 +  8 + kc]), accx1, 0, 0, 0);
        accx2 = __builtin_amdgcn_mfma_f32_16x16x32_bf16(a, __builtin_bit_cast(bf16x8, Braw[32 + 16 + kc]), accx2, 0, 0, 0);
        accx3 = __builtin_amdgcn_mfma_f32_16x16x32_bf16(a, __builtin_bit_cast(bf16x8, Braw[32 + 24 + kc]), accx3, 0, 0, 0);
      }
      {
        int tn = (t + 2 < S_LEN) ? (t + 2) : (S_LEN - 1);
        const float* xp = x + ((size_t)(tn * BATCH + m_base + l16)) * HID + kbase + kq8;
#pragma unroll
        for (int kc = 0; kc < 8; ++kc) {
          float4 lo = *(const float4*)(xp + kc * 32);
          float4 hi = *(const float4*)(xp + kc * 32 + 4);
          Araw_x[kc] = cvt8(lo, hi);
        }
      }
    } else {
      size_t oi = ((size_t)(t * BATCH + b_glob)) * HID + j_t;
      out[oi] = x[oi] + h;
      out[(size_t)SBH + (size_t)b_glob * HID + j_t] = h;         // h_f
      out[(size_t)SBH + BH + (size_t)b_glob * HID + j_t] = c;    // c_f
    }
  }
}

extern "C" void kernel_launch(void* const* d_in, const int* in_sizes, int n_in,
                              void* d_out, int out_size, void* d_ws, size_t ws_size,
                              hipStream_t stream) {
  const float* x   = (const float*)d_in[0];
  const float* h0  = (const float*)d_in[1];
  const float* c0  = (const float*)d_in[2];
  const float* Wf  = (const float*)d_in[3];
  const float* bf_ = (const float*)d_in[4];
  const float* Wi  = (const float*)d_in[5];
  const float* bi_ = (const float*)d_in[6];
  const float* Wg  = (const float*)d_in[7];
  const float* bg_ = (const float*)d_in[8];
  const float* Wo  = (const float*)d_in[9];
  const float* bo_ = (const float*)d_in[10];

  char* ws = (char*)d_ws;
  size_t off = 0;
  __bf16* w_x  = (__bf16*)(ws + off); off += (size_t)4 * 1024 * 1024 * 2;  // 8 MB
  __bf16* w_h  = (__bf16*)(ws + off); off += (size_t)4 * 1024 * 1024 * 2;  // 8 MB
  __bf16* h_buf = (__bf16*)(ws + off); off += (size_t)2 * BH * 2;          // 256 KB
  if (ws_size < off) return;

  float* out = (float*)d_out;

  prep_kernel<<<2048, 256, 0, stream>>>(h0, Wf, Wi, Wg, Wo, w_x, w_h, h_buf);
  lstm_kernel<<<NWG, 256, 0, stream>>>(x, c0, bf_, bi_, bg_, bo_, w_x, w_h, h_buf, out);
}

// Round 10
// 1230.818 us; speedup vs baseline: 2.5716x; 1.5232x over previous
//
#include <hip/hip_runtime.h>

typedef __bf16 bf16x8 __attribute__((ext_vector_type(8)));
typedef float f32x4 __attribute__((ext_vector_type(4)));
typedef unsigned int u32x4 __attribute__((ext_vector_type(4)));

#define S_LEN 256
#define BATCH 64
#define HID   1024
#define NWG   256
#define SBH   (S_LEN * BATCH * HID)   /* 16777216 */
#define BH    (BATCH * HID)           /* 65536 */

__device__ __forceinline__ float sigm(float v) { return 1.0f / (1.0f + __expf(-v)); }
__device__ __forceinline__ float tanh_fast(float v) {
  float e = __expf(-2.0f * __builtin_fabsf(v));
  float r = (1.0f - e) / (1.0f + e);
  return __builtin_copysignf(r, v);
}

// Pack 8 f32 -> 8 bf16 (RNE via compiler cvt) into one 16B word.
__device__ __forceinline__ u32x4 cvt8(float4 a, float4 b) {
  union { unsigned short us[8]; u32x4 v; } r;
  r.us[0] = __builtin_bit_cast(unsigned short, (__bf16)a.x);
  r.us[1] = __builtin_bit_cast(unsigned short, (__bf16)a.y);
  r.us[2] = __builtin_bit_cast(unsigned short, (__bf16)a.z);
  r.us[3] = __builtin_bit_cast(unsigned short, (__bf16)a.w);
  r.us[4] = __builtin_bit_cast(unsigned short, (__bf16)b.x);
  r.us[5] = __builtin_bit_cast(unsigned short, (__bf16)b.y);
  r.us[6] = __builtin_bit_cast(unsigned short, (__bf16)b.z);
  r.us[7] = __builtin_bit_cast(unsigned short, (__bf16)b.w);
  return r.v;
}

// 8 x global_load_dwordx4 + internal vmcnt(0), ONE asm block.
// PROVEN SAFE pattern: no in-flight registers are ever visible to regalloc
// (r5/r6: split issue/wait across compiler code is unsound at this pressure).
#define LOAD8_X4(dst, base, MODS)                                             \
  asm volatile(                                                               \
      "global_load_dwordx4 %0, %8, off offset:0 " MODS "\n\t"                 \
      "global_load_dwordx4 %1, %8, off offset:64 " MODS "\n\t"                \
      "global_load_dwordx4 %2, %8, off offset:128 " MODS "\n\t"               \
      "global_load_dwordx4 %3, %8, off offset:192 " MODS "\n\t"               \
      "global_load_dwordx4 %4, %8, off offset:256 " MODS "\n\t"               \
      "global_load_dwordx4 %5, %8, off offset:320 " MODS "\n\t"               \
      "global_load_dwordx4 %6, %8, off offset:384 " MODS "\n\t"               \
      "global_load_dwordx4 %7, %8, off offset:448 " MODS "\n\t"               \
      "s_waitcnt vmcnt(0)"                                                    \
      : "=&v"((dst)[0]), "=&v"((dst)[1]), "=&v"((dst)[2]), "=&v"((dst)[3]),   \
        "=&v"((dst)[4]), "=&v"((dst)[5]), "=&v"((dst)[6]), "=&v"((dst)[7])    \
      : "v"(base)                                                             \
      : "memory")

#define CHECK8(H, MEXP, BAD)                                                  \
  do {                                                                        \
    BAD = 0;                                                                  \
    _Pragma("unroll")                                                         \
    for (int _kc = 0; _kc < 8; ++_kc) {                                       \
      u32x4 _w = (H)[_kc];                                                    \
      BAD |= ((_w[0] ^ (MEXP)) & 0x00010001u);                                \
      BAD |= ((_w[1] ^ (MEXP)) & 0x00010001u);                                \
      BAD |= ((_w[2] ^ (MEXP)) & 0x00010001u);                                \
      BAD |= ((_w[3] ^ (MEXP)) & 0x00010001u);                                \
    }                                                                         \
  } while (0)

#define HMFMA(H)                                                              \
  do {                                                                        \
    _Pragma("unroll")                                                         \
    for (int _kc = 0; _kc < 8; ++_kc) {                                       \
      bf16x8 _a = __builtin_bit_cast(bf16x8, (H)[_kc]);                       \
      acc0 = __builtin_amdgcn_mfma_f32_16x16x32_bf16(_a, __builtin_bit_cast(bf16x8, Braw[ 0 + _kc]), acc0, 0, 0, 0); \
      acc1 = __builtin_amdgcn_mfma_f32_16x16x32_bf16(_a, __builtin_bit_cast(bf16x8, Braw[ 8 + _kc]), acc1, 0, 0, 0); \
      acc2 = __builtin_amdgcn_mfma_f32_16x16x32_bf16(_a, __builtin_bit_cast(bf16x8, Braw[16 + _kc]), acc2, 0, 0, 0); \
      acc3 = __builtin_amdgcn_mfma_f32_16x16x32_bf16(_a, __builtin_bit_cast(bf16x8, Braw[24 + _kc]), acc3, 0, 0, 0); \
    }                                                                         \
  } while (0)

#define XMFMA()                                                               \
  do {                                                                        \
    _Pragma("unroll")                                                         \
    for (int _kc = 0; _kc < 8; ++_kc) {                                       \
      bf16x8 _a = __builtin_bit_cast(bf16x8, Araw_x[_kc]);                    \
      accx0 = __builtin_amdgcn_mfma_f32_16x16x32_bf16(_a, __builtin_bit_cast(bf16x8, Braw[32 +  0 + _kc]), accx0, 0, 0, 0); \
      accx1 = __builtin_amdgcn_mfma_f32_16x16x32_bf16(_a, __builtin_bit_cast(bf16x8, Braw[32 +  8 + _kc]), accx1, 0, 0, 0); \
      accx2 = __builtin_amdgcn_mfma_f32_16x16x32_bf16(_a, __builtin_bit_cast(bf16x8, Braw[32 + 16 + _kc]), accx2, 0, 0, 0); \
      accx3 = __builtin_amdgcn_mfma_f32_16x16x32_bf16(_a, __builtin_bit_cast(bf16x8, Braw[32 + 24 + _kc]), accx3, 0, 0, 0); \
    }                                                                         \
  } while (0)

// Vectorized prep (r2-proven): x -> bf16 staging (makes per-step x frag reads
// L3 hits — r9 showed dropping this costs ~0.8ms), weight layout conversion,
// h0 seed with epoch bit0=0, region-1 poison bit0=1.
__global__ void prep_kernel(const float* __restrict__ x, const float* __restrict__ h0,
                            const float* __restrict__ Wf, const float* __restrict__ Wi,
                            const float* __restrict__ Wg, const float* __restrict__ Wo,
                            __bf16* __restrict__ x_bf, __bf16* __restrict__ w_x,
                            __bf16* __restrict__ w_h, __bf16* __restrict__ h_buf) {
  size_t tid = (size_t)blockIdx.x * blockDim.x + threadIdx.x;
  size_t stride = (size_t)gridDim.x * blockDim.x;     // 524288 threads

  for (size_t i = tid; i < (size_t)(SBH / 8); i += stride) {
    const float4* s = (const float4*)x + i * 2;
    ((u32x4*)x_bf)[i] = cvt8(s[0], s[1]);
  }

#define W_CONV(W, gidx)                                                        \
  for (size_t i = tid; i < (size_t)(1024 * 128); i += stride) {                \
    int j   = (int)(i >> 7);                                                   \
    int kc8 = (int)(i & 127);                                                  \
    const float* row = (W) + (size_t)j * 2048;                                 \
    const float4* sx = (const float4*)(row + kc8 * 8);                         \
    const float4* sh = (const float4*)(row + 1024 + kc8 * 8);                  \
    size_t dst = (size_t)((gidx) * 1024 + j) * 128 + kc8;                      \
    ((u32x4*)w_x)[dst] = cvt8(sx[0], sx[1]);                                   \
    ((u32x4*)w_h)[dst] = cvt8(sh[0], sh[1]);                                   \
  }
  W_CONV(Wf, 0)
  W_CONV(Wi, 1)
  W_CONV(Wg, 2)
  W_CONV(Wo, 3)
#undef W_CONV

  // h0 -> bf16, bit0 cleared (epoch marker 0 for consume-step 0)
  for (size_t i = tid; i < (size_t)(BH / 8); i += stride) {
    const float4* s = (const float4*)h0 + i * 2;
    u32x4 v = cvt8(s[0], s[1]);
    v &= 0xFFFEFFFEu;
    ((u32x4*)h_buf)[i] = v;
  }

  // region 1 poison: bit0=1 everywhere (stale vs first producer marker 0)
  for (size_t i = tid; i < (size_t)(BH / 8); i += stride) {
    u32x4 p = {0x00010001u, 0x00010001u, 0x00010001u, 0x00010001u};
    ((u32x4*)(h_buf + BH))[i] = p;
  }
}

// v10 = v4 (proven 957us: x_bf staging, epoch-marker protocol, one-asm-block
// poll) + XOR-swizzled zbuf (proven: conflicts 1.68e7 -> 0) + TOP-OF-LOOP VMEM
// ISSUE: the out-write's x[oi] read, the x-side MFMA, and the x(t+2) stage
// loads all move to immediately after poll-accept. Their latency lands under
// hMFMA+LDS+combine+publish (~1.5-2us) instead of being serially drained by
// the next poll's vmcnt(0) (r9 lesson: everything in-flight at the poll is
// paid for on the critical path).
__global__ __launch_bounds__(256, 1) void lstm_kernel(
    const float* __restrict__ x, const float* __restrict__ c0,
    const float* __restrict__ bfp, const float* __restrict__ bip,
    const float* __restrict__ bgp, const float* __restrict__ bop,
    const __bf16* __restrict__ x_bf, const __bf16* __restrict__ w_x,
    const __bf16* __restrict__ w_h, __bf16* __restrict__ h_buf,
    float* __restrict__ out) {
  const int tid    = threadIdx.x;
  const int wgid   = blockIdx.x;
  const int m_idx  = wgid & 3;
  const int m_base = m_idx * 16;
  const int U      = (wgid >> 2) * 16;
  const int wave   = tid >> 6;
  const int lane   = tid & 63;
  const int l16    = lane & 15;
  const int kq8    = (lane >> 4) * 8;
  const int kbase  = wave * 256;

  __shared__ float zbuf[2][4][16][64];       // XOR-swizzled, no pad
  __shared__ unsigned short hpack[16][16];

  // ---- Resident B: 64 frags. [0..31] = Wh (4 gates x 8 kc), [32..63] = Wx ----
  u32x4 Braw[64];
#pragma unroll
  for (int n = 0; n < 4; ++n) {
    unsigned long gbh =
        (unsigned long)(w_h + (size_t)(n * 1024 + U + l16) * HID + kbase + kq8);
    LOAD8_X4(&Braw[n * 8], gbh, "");
  }
#pragma unroll
  for (int n = 0; n < 4; ++n) {
    unsigned long gbx =
        (unsigned long)(w_x + (size_t)(n * 1024 + U + l16) * HID + kbase + kq8);
    LOAD8_X4(&Braw[32 + n * 8], gbx, "");
  }

  const int b_loc  = tid >> 4;
  const int u_loc  = tid & 15;
  const int j_t    = U + u_loc;
  const int b_glob = m_base + b_loc;
  float c = c0[(size_t)b_glob * HID + j_t];
  const float bias_f = bfp[j_t], bias_i = bip[j_t], bias_g = bgp[j_t], bias_o = bop[j_t];

  // ---- Prologue: x(0) partials; x(1) staged ----
  u32x4 Araw_x[8];
  {
    const __bf16* xp = x_bf + (size_t)(m_base + l16) * HID + kbase + kq8;
#pragma unroll
    for (int kc = 0; kc < 8; ++kc) Araw_x[kc] = *(const u32x4*)(xp + kc * 32);
  }
  f32x4 accx0 = {0,0,0,0}, accx1 = {0,0,0,0}, accx2 = {0,0,0,0}, accx3 = {0,0,0,0};
  XMFMA();
  {
    const __bf16* xp = x_bf + (size_t)(BATCH + m_base + l16) * HID + kbase + kq8;
#pragma unroll
    for (int kc = 0; kc < 8; ++kc) Araw_x[kc] = *(const u32x4*)(xp + kc * 32);
  }

  const unsigned long ga_base =
      (unsigned long)(h_buf + (size_t)(m_base + l16) * HID + kbase + kq8);

  for (int t = 0; t < S_LEN; ++t) {
    const size_t roff = (t & 1) ? (size_t)BH : 0;
    const unsigned mexp = ((unsigned)(t >> 1) & 1u) * 0x00010001u;
    const unsigned long ga = ga_base + roff * 2;   // bf16 -> bytes
    const int zp = t & 1;
    const size_t oi = ((size_t)(t * BATCH + b_glob)) * HID + j_t;

    // ---- Accept h: one-asm-block load + marker check; stale => full reload ----
    u32x4 Ah[8];
    {
      LOAD8_X4(Ah, ga, "sc0 sc1");
      unsigned bad;
      CHECK8(Ah, mexp, bad);
      if (__builtin_expect(__ballot(bad != 0) != 0ull, 0)) {
        do {
          __builtin_amdgcn_s_sleep(1);
          LOAD8_X4(Ah, ga, "sc0 sc1");
          CHECK8(Ah, mexp, bad);
        } while (__ballot(bad != 0) != 0ull);
      }
    }

    // ---- TOP-OF-LOOP VMEM: x[oi] for the out-write (lands under compute) ----
    float xv = x[oi];

    // ---- acc = x partials for step t; MFMA work (h-side + x-side for t+1) ----
    f32x4 acc0 = accx0, acc1 = accx1, acc2 = accx2, acc3 = accx3;
    HMFMA(Ah);
    accx0 = (f32x4){0,0,0,0}; accx1 = (f32x4){0,0,0,0};
    accx2 = (f32x4){0,0,0,0}; accx3 = (f32x4){0,0,0,0};
    XMFMA();                                   // consumes Araw_x = x(t+1)

    // ---- TOP-OF-LOOP VMEM: stage x(t+2) (L3-resident; lands under compute) ----
    {
      int tn = (t + 2 < S_LEN) ? (t + 2) : (S_LEN - 1);
      const __bf16* xp =
          x_bf + ((size_t)(tn * BATCH + m_base + l16)) * HID + kbase + kq8;
#pragma unroll
      for (int kc = 0; kc < 8; ++kc) Araw_x[kc] = *(const u32x4*)(xp + kc * 32);
    }

    // ---- z partials to LDS (XOR-swizzled: conflicts == 0, proven) ----
    {
      int q = lane >> 4;
#pragma unroll
      for (int r = 0; r < 4; ++r) {
        int row = q * 4 + r;
        int s = ((row ^ (row >> 2)) & 3) << 4;
        zbuf[zp][wave][row][( 0 + l16) ^ s] = acc0[r];
        zbuf[zp][wave][row][(16 + l16) ^ s] = acc1[r];
        zbuf[zp][wave][row][(32 + l16) ^ s] = acc2[r];
        zbuf[zp][wave][row][(48 + l16) ^ s] = acc3[r];
      }
    }
    __syncthreads();   // the only intra-WG barrier per step

    // ---- Combine gates, update c, h ----
    float h;
    {
      const int row = b_loc;
      const int s = ((row ^ (row >> 2)) & 3) << 4;
      float zf = 0.f, zi = 0.f, zg = 0.f, zo = 0.f;
#pragma unroll
      for (int w = 0; w < 4; ++w) {
        zf += zbuf[zp][w][row][( 0 + u_loc) ^ s];
        zi += zbuf[zp][w][row][(16 + u_loc) ^ s];
        zg += zbuf[zp][w][row][(32 + u_loc) ^ s];
        zo += zbuf[zp][w][row][(48 + u_loc) ^ s];
      }
      float fg = sigm(zf + bias_f);
      float ig = sigm(zi + bias_i);
      float gg = tanh_fast(zg + bias_g);
      float og = sigm(zo + bias_o);
      c = fg * c + ig * gg;
      h = og * tanh_fast(c);
    }

    if (t < S_LEN - 1) {
      const size_t woff = (t & 1) ? 0 : (size_t)BH;

      // ---- Publish h with next epoch marker (fire-and-forget) ----
      {
        unsigned short hbv = __builtin_bit_cast(unsigned short, (__bf16)h);
        hbv = (unsigned short)((hbv & 0xFFFEu) | (unsigned)(((t + 1) >> 1) & 1));
        hpack[b_loc][u_loc] = hbv;
      }
      asm volatile("s_waitcnt lgkmcnt(0)" ::: "memory");
      __builtin_amdgcn_sched_barrier(0);
      if (lane < 8) {
        int b = 4 * wave + (lane >> 1), half = lane & 1;
        u32x4 hv = *(const u32x4*)(&hpack[b][half * 8]);
        unsigned long ha = (unsigned long)(h_buf + woff +
                                           (size_t)(m_base + b) * HID + U + half * 8);
        asm volatile("global_store_dwordx4 %0, %1, off sc0 sc1"
                     :: "v"(ha), "v"(hv) : "memory");
      }

      // ---- out-write (xv already in registers; store commit only) ----
      out[oi] = xv + h;
    } else {
      out[oi] = xv + h;
      out[(size_t)SBH + (size_t)b_glob * HID + j_t] = h;         // h_f
      out[(size_t)SBH + BH + (size_t)b_glob * HID + j_t] = c;    // c_f
    }
  }
}

extern "C" void kernel_launch(void* const* d_in, const int* in_sizes, int n_in,
                              void* d_out, int out_size, void* d_ws, size_t ws_size,
                              hipStream_t stream) {
  const float* x   = (const float*)d_in[0];
  const float* h0  = (const float*)d_in[1];
  const float* c0  = (const float*)d_in[2];
  const float* Wf  = (const float*)d_in[3];
  const float* bf_ = (const float*)d_in[4];
  const float* Wi  = (const float*)d_in[5];
  const float* bi_ = (const float*)d_in[6];
  const float* Wg  = (const float*)d_in[7];
  const float* bg_ = (const float*)d_in[8];
  const float* Wo  = (const float*)d_in[9];
  const float* bo_ = (const float*)d_in[10];

  char* ws = (char*)d_ws;
  size_t off = 0;
  __bf16* x_bf = (__bf16*)(ws + off); off += (size_t)SBH * 2;              // 32 MB
  __bf16* w_x  = (__bf16*)(ws + off); off += (size_t)4 * 1024 * 1024 * 2;  // 8 MB
  __bf16* w_h  = (__bf16*)(ws + off); off += (size_t)4 * 1024 * 1024 * 2;  // 8 MB
  __bf16* h_buf = (__bf16*)(ws + off); off += (size_t)2 * BH * 2;          // 256 KB
  if (ws_size < off) return;

  float* out = (float*)d_out;

  prep_kernel<<<2048, 256, 0, stream>>>(x, h0, Wf, Wi, Wg, Wo, x_bf, w_x, w_h, h_buf);
  lstm_kernel<<<NWG, 256, 0, stream>>>(x, c0, bf_, bi_, bg_, bo_, x_bf, w_x, w_h, h_buf, out);
}